// Round 2
// baseline (124.631 us; speedup 1.0000x reference)
//
#include <hip/hip_runtime.h>

// x (B=4, S=8192, D=2048) f32, filters (FO=2, B=4, S=8192, K=3) f32.
// out[b,t,c] = k[b,2]*x[b,t,c] + k[b,1]*x[b,t-1,c] + k[b,0]*x[b,t-2,c]
// k[b,j] = (1/S) * sum_{fo,s} filters[fo,b,s,j].
//
// Fused single-launch version: blocks 0..63 perform the filter reduction
// (round-0 stage 1, LDS tree replaced by wave shuffles) and publish via a
// device-scope release atomic; every block prefetches its x carry rows,
// then spin-waits (acquire) for the 64 partials before folding k and
// running the round-0 conv body (256 thr, 2 carry pipelines, no swizzle —
// the proven-best 93.8 us configuration).

constexpr int B_ = 4;
constexpr int S_ = 8192;
constexpr int D_ = 2048;
constexpr int TC = 32;          // t-chunk per conv block
constexpr int LD4 = D_ / 4;     // 512 float4 per row

typedef float f4 __attribute__((ext_vector_type(4)));

__global__ __launch_bounds__(256) void fused_conv_kernel(
    const float* __restrict__ x, const float* __restrict__ filters,
    float* __restrict__ out, float* __restrict__ partials,
    unsigned* __restrict__ flag) {
    const int bid = blockIdx.x;
    const int tid = threadIdx.x;

    // ---------------- phase A: blocks 0..63 reduce one (fo,b,slice) plane
    if (bid < 64) {
        const int fo    = bid >> 5;
        const int fb    = (bid >> 3) & 3;
        const int slice = bid & 7;
        const f4* F = (const f4*)filters;
        const int base_f4 = (fo * 4 + fb) * 6144 + slice * 768;  // float4 units

        const f4 a  = F[base_f4 + 3 * tid + 0];
        const f4 bb = F[base_f4 + 3 * tid + 1];
        const f4 c  = F[base_f4 + 3 * tid + 2];

        float s0 = a.x + a.w + bb.z + c.y;
        float s1 = a.y + bb.x + bb.w + c.z;
        float s2 = a.z + bb.y + c.x + c.w;

        // wave64 butterfly reduce
        #pragma unroll
        for (int off = 32; off > 0; off >>= 1) {
            s0 += __shfl_xor(s0, off);
            s1 += __shfl_xor(s1, off);
            s2 += __shfl_xor(s2, off);
        }
        __shared__ float wred[4][3];
        const int wv = tid >> 6;
        if ((tid & 63) == 0) {
            wred[wv][0] = s0; wred[wv][1] = s1; wred[wv][2] = s2;
        }
        __syncthreads();
        if (tid < 3) {
            partials[bid * 3 + tid] =
                wred[0][tid] + wred[1][tid] + wred[2][tid] + wred[3][tid];
            __threadfence();   // make partials visible device-wide
        }
        __syncthreads();
        if (tid == 0)
            __hip_atomic_fetch_add(flag, 1u, __ATOMIC_RELEASE,
                                   __HIP_MEMORY_SCOPE_AGENT);
    }

    // ---------------- phase B: causal conv for chunk bid (all 1024 blocks)
    const int nchunk = S_ / TC;          // 256
    const int tchunk = bid % nchunk;
    const int b      = bid / nchunk;
    const int t0     = tchunk * TC;

    const f4* xb = (const f4*)x + (size_t)b * S_ * LD4;
    f4*       ob = (f4*)out     + (size_t)b * S_ * LD4;
    const int ca = tid;          // first half of row
    const int cb = tid + 256;    // second half of row

    // prefetch carry rows BEFORE waiting on the flag: the reduce latency
    // hides under these (and the subsequent group-0) load round-trips.
    f4 z = (f4)(0.f);
    f4 am2 = (t0 >= 2) ? xb[(size_t)(t0 - 2) * LD4 + ca] : z;
    f4 am1 = (t0 >= 1) ? xb[(size_t)(t0 - 1) * LD4 + ca] : z;
    f4 bm2 = (t0 >= 2) ? xb[(size_t)(t0 - 2) * LD4 + cb] : z;
    f4 bm1 = (t0 >= 1) ? xb[(size_t)(t0 - 1) * LD4 + cb] : z;

    // wait for all 64 partials (device-scope acquire; s_sleep backoff)
    if (tid == 0) {
        while (__hip_atomic_load(flag, __ATOMIC_ACQUIRE,
                                 __HIP_MEMORY_SCOPE_AGENT) < 64u)
            __builtin_amdgcn_s_sleep(2);
    }
    __syncthreads();

    __shared__ float ksh[3];
    if (tid < 3) {
        float s = 0.f;
        #pragma unroll
        for (int fo = 0; fo < 2; ++fo)
            #pragma unroll
            for (int sl = 0; sl < 8; ++sl)
                s += partials[(fo * 32 + b * 8 + sl) * 3 + tid];
        ksh[tid] = s * (1.0f / (float)S_);
    }
    __syncthreads();
    const float k0 = ksh[0], k1 = ksh[1], k2 = ksh[2];

    #pragma unroll
    for (int g = 0; g < TC / 4; ++g) {
        f4 xa[4], xv[4];
        #pragma unroll
        for (int u = 0; u < 4; ++u) {
            const size_t t = (size_t)(t0 + g * 4 + u);
            xa[u] = xb[t * LD4 + ca];
            xv[u] = xb[t * LD4 + cb];
        }
        #pragma unroll
        for (int u = 0; u < 4; ++u) {
            const size_t t = (size_t)(t0 + g * 4 + u);
            f4 oa = k2 * xa[u] + k1 * am1 + k0 * am2;
            f4 ov = k2 * xv[u] + k1 * bm1 + k0 * bm2;
            __builtin_nontemporal_store(oa, &ob[t * LD4 + ca]);
            __builtin_nontemporal_store(ov, &ob[t * LD4 + cb]);
            am2 = am1; am1 = xa[u];
            bm2 = bm1; bm1 = xv[u];
        }
    }
}

extern "C" void kernel_launch(void* const* d_in, const int* in_sizes, int n_in,
                              void* d_out, int out_size, void* d_ws, size_t ws_size,
                              hipStream_t stream) {
    const float* x       = (const float*)d_in[0];
    const float* filters = (const float*)d_in[1];
    float*       out     = (float*)d_out;
    float*       partials = (float*)d_ws;                       // 192 floats
    unsigned*    flag     = (unsigned*)((char*)d_ws + 1024);    // past partials

    // zero the readiness flag each iteration (workspace contents are not
    // guaranteed across iterations; stale flag would fake readiness)
    hipMemsetAsync(flag, 0, sizeof(unsigned), stream);

    const int nblocks = B_ * (S_ / TC);  // 1024
    fused_conv_kernel<<<nblocks, 256, 0, stream>>>(x, filters, out,
                                                   partials, flag);
}

// Round 3
// 93.898 us; speedup vs baseline: 1.3273x; 1.3273x over previous
//
#include <hip/hip_runtime.h>

// x (B=4, S=8192, D=2048) f32, filters (FO=2, B=4, S=8192, K=3) f32.
// out[b,t,c] = k[b,2]*x[b,t,c] + k[b,1]*x[b,t-1,c] + k[b,0]*x[b,t-2,c]
// k[b,j] = (1/S) * sum_{fo,s} filters[fo,b,s,j].
//
// ROOFLINE CONFIG (R0, 93.8 us): conv kernel moves 537 MB app-level at
// ~6.15 TB/s = ~98% of the measured float4-copy ceiling (6.29 TB/s).
// R1 (512thr + XCD swizzle, 100 us) and R2 (fused spin-wait, 124.6 us)
// both regressed: the memory system is saturated at 16 waves/CU; added
// concurrency or coherence traffic is net-negative.

constexpr int B_ = 4;
constexpr int S_ = 8192;
constexpr int D_ = 2048;
constexpr int K_ = 3;
constexpr int TC = 32;          // t-chunk per conv block
constexpr int LD4 = D_ / 4;     // 512 float4 per row

typedef float f4 __attribute__((ext_vector_type(4)));

// ---------------- stage 1: parallel partial reduction of filters ----------
// 64 blocks: bid -> fo = bid>>5, b = (bid>>3)&3, slice = bid&7.
// Each block reads a contiguous 1024-s slice of one (fo,b) plane as 256
// groups of 3 float4 (= 4 complete K-triples); float j in a group has
// kk = j % 3 since all base offsets are divisible by 3.
__global__ __launch_bounds__(256) void reduce_partial_kernel(
    const float* __restrict__ filters, float* __restrict__ partials) {
    const int bid   = blockIdx.x;
    const int tid   = threadIdx.x;
    const int fo    = bid >> 5;
    const int b     = (bid >> 3) & 3;
    const int slice = bid & 7;

    const f4* F = (const f4*)filters;
    const int base_f4 = (fo * 4 + b) * 6144 + slice * 768;  // in float4 units

    const f4 a  = F[base_f4 + 3 * tid + 0];
    const f4 bb = F[base_f4 + 3 * tid + 1];
    const f4 c  = F[base_f4 + 3 * tid + 2];

    float s0 = a.x + a.w + bb.z + c.y;
    float s1 = a.y + bb.x + bb.w + c.z;
    float s2 = a.z + bb.y + c.x + c.w;

    __shared__ float red[3][256];
    red[0][tid] = s0; red[1][tid] = s1; red[2][tid] = s2;
    __syncthreads();
    for (int off = 128; off > 0; off >>= 1) {
        if (tid < off) {
            red[0][tid] += red[0][tid + off];
            red[1][tid] += red[1][tid + off];
            red[2][tid] += red[2][tid + off];
        }
        __syncthreads();
    }
    if (tid < 3) partials[bid * 3 + tid] = red[tid][0];
}

// ---------------- stage 2: causal conv, full-row blocks -------------------
// Each block owns a full 8KB row-span for TC t-steps: thread handles
// c4 = tid and c4 = tid+256 (two register carry-pipelines). Every
// instantaneous wave burst spans the full row -> uniform channel coverage.
__global__ __launch_bounds__(256) void causal_conv_kernel(
    const float* __restrict__ x, const float* __restrict__ partials,
    float* __restrict__ out) {
    const int bid    = blockIdx.x;
    const int tid    = threadIdx.x;
    const int nchunk = S_ / TC;          // 256
    const int tchunk = bid % nchunk;
    const int b      = bid / nchunk;
    const int t0     = tchunk * TC;

    // fold the 16 partials (2 fo * 8 slices) for this batch
    __shared__ float ksh[3];
    if (tid < 3) {
        float s = 0.f;
        #pragma unroll
        for (int fo = 0; fo < 2; ++fo)
            #pragma unroll
            for (int sl = 0; sl < 8; ++sl)
                s += partials[(fo * 32 + b * 8 + sl) * 3 + tid];
        ksh[tid] = s * (1.0f / (float)S_);
    }
    __syncthreads();
    const float k0 = ksh[0], k1 = ksh[1], k2 = ksh[2];

    const f4* xb = (const f4*)x + (size_t)b * S_ * LD4;
    f4*       ob = (f4*)out     + (size_t)b * S_ * LD4;
    const int ca = tid;          // first half of row
    const int cb = tid + 256;    // second half of row

    f4 z = (f4)(0.f);
    f4 am2 = (t0 >= 2) ? xb[(size_t)(t0 - 2) * LD4 + ca] : z;
    f4 am1 = (t0 >= 1) ? xb[(size_t)(t0 - 1) * LD4 + ca] : z;
    f4 bm2 = (t0 >= 2) ? xb[(size_t)(t0 - 2) * LD4 + cb] : z;
    f4 bm1 = (t0 >= 1) ? xb[(size_t)(t0 - 1) * LD4 + cb] : z;

    #pragma unroll
    for (int g = 0; g < TC / 4; ++g) {
        f4 xa[4], xv[4];
        #pragma unroll
        for (int u = 0; u < 4; ++u) {
            const size_t t = (size_t)(t0 + g * 4 + u);
            xa[u] = xb[t * LD4 + ca];
            xv[u] = xb[t * LD4 + cb];
        }
        #pragma unroll
        for (int u = 0; u < 4; ++u) {
            const size_t t = (size_t)(t0 + g * 4 + u);
            f4 oa = k2 * xa[u] + k1 * am1 + k0 * am2;
            f4 ov = k2 * xv[u] + k1 * bm1 + k0 * bm2;
            __builtin_nontemporal_store(oa, &ob[t * LD4 + ca]);
            __builtin_nontemporal_store(ov, &ob[t * LD4 + cb]);
            am2 = am1; am1 = xa[u];
            bm2 = bm1; bm1 = xv[u];
        }
    }
}

extern "C" void kernel_launch(void* const* d_in, const int* in_sizes, int n_in,
                              void* d_out, int out_size, void* d_ws, size_t ws_size,
                              hipStream_t stream) {
    const float* x        = (const float*)d_in[0];
    const float* filters  = (const float*)d_in[1];
    float*       out      = (float*)d_out;
    float*       partials = (float*)d_ws;   // 64*3 = 192 floats

    reduce_partial_kernel<<<64, 256, 0, stream>>>(filters, partials);

    const int nblocks = B_ * (S_ / TC);  // 1024
    causal_conv_kernel<<<nblocks, 256, 0, stream>>>(x, partials, out);
}